// Round 12
// baseline (19564.835 us; speedup 1.0000x reference)
//
#include <hip/hip_runtime.h>

#define RS 1024   // reservoir
#define SL 4096   // seq len
#define NB 1024   // batch
#define NI 16     // input size

typedef short s8v __attribute__((ext_vector_type(8)));
typedef float f16v __attribute__((ext_vector_type(16)));
typedef unsigned int u4v __attribute__((ext_vector_type(4)));

#define WAIT_VM(N) do { asm volatile("s_waitcnt vmcnt(" #N ")" ::: "memory"); \
                        __builtin_amdgcn_sched_barrier(0); } while (0)

static __device__ __forceinline__ unsigned short f2bf(float f) {
  unsigned u = __float_as_uint(f);
  u += 0x7fffu + ((u >> 16) & 1u);          // round-to-nearest-even
  return (unsigned short)(u >> 16);
}
static __device__ __forceinline__ float bf2f(unsigned short b) {
  return __uint_as_float(((unsigned)b) << 16);
}
static __device__ __forceinline__ float fast_tanh(float a) {
  float e = __expf(2.0f * a);
  return 1.0f - 2.0f / (e + 1.0f);
}

// ---- L1+L2-bypassing ops (sc0 sc1): coherent at the LLC ----
static __device__ __forceinline__ u4v ld_llc_b128(const void* p) {
  u4v d;
  asm volatile("global_load_dwordx4 %0, %1, off sc0 sc1"
               : "=v"(d) : "v"(p) : "memory");
  return d;
}
static __device__ __forceinline__ u4v ld_llc_b128_sync(const void* p) {
  u4v d;
  asm volatile("global_load_dwordx4 %0, %1, off sc0 sc1\n\ts_waitcnt vmcnt(0)"
               : "=v"(d) : "v"(p) : "memory");
  return d;
}
static __device__ __forceinline__ void st_llc_b128(void* p, u4v d) {
  asm volatile("global_store_dwordx4 %0, %1, off sc0 sc1"
               : : "v"(p), "v"(d) : "memory");
}
static __device__ __forceinline__ void st_llc_b32(void* p, int d) {
  asm volatile("global_store_dword %0, %1, off sc0 sc1"
               : : "v"(p), "v"(d) : "memory");
}
static __device__ __forceinline__ int min16v(u4v a, u4v b, u4v c, u4v d) {
  int m = min(min(min((int)a.x, (int)a.y), min((int)a.z, (int)a.w)),
              min(min((int)b.x, (int)b.y), min((int)b.z, (int)b.w)));
  int n = min(min(min((int)c.x, (int)c.y), min((int)c.z, (int)c.w)),
              min(min((int)d.x, (int)d.y), min((int)d.z, (int)d.w)));
  return min(m, n);
}
static __device__ __forceinline__ void poll_issue(const void* p, u4v& a, u4v& b,
                                                  u4v& c, u4v& d) {
  asm volatile("global_load_dwordx4 %0, %4, off sc0 sc1\n\t"
               "global_load_dwordx4 %1, %4, off offset:16 sc0 sc1\n\t"
               "global_load_dwordx4 %2, %4, off offset:32 sc0 sc1\n\t"
               "global_load_dwordx4 %3, %4, off offset:48 sc0 sc1"
               : "=v"(a), "=v"(b), "=v"(c), "=v"(d) : "v"(p) : "memory");
}
static __device__ __forceinline__ int min16_block(const void* p) {
  u4v a, b, c, d;
  asm volatile("global_load_dwordx4 %0, %4, off sc0 sc1\n\t"
               "global_load_dwordx4 %1, %4, off offset:16 sc0 sc1\n\t"
               "global_load_dwordx4 %2, %4, off offset:32 sc0 sc1\n\t"
               "global_load_dwordx4 %3, %4, off offset:48 sc0 sc1\n\t"
               "s_waitcnt vmcnt(0)"
               : "=v"(a), "=v"(b), "=v"(c), "=v"(d) : "v"(p) : "memory");
  return min16v(a, b, c, d);
}

// prep: W fp32->bf16 (plain); zero h0 + flags via sc0sc1 (coherent with esn)
__global__ __launch_bounds__(256) void prep_kernel(
    const float* __restrict__ W, unsigned short* __restrict__ wbf,
    char* __restrict__ h0, int* __restrict__ flags) {
  int idx = blockIdx.x * 256 + threadIdx.x;
  if (idx < RS * RS) wbf[idx] = f2bf(W[idx]);
  if (idx < (NB * RS) / 8) {
    u4v z = {0u, 0u, 0u, 0u};
    st_llc_b128(h0 + (size_t)idx * 16, z);
  }
  if (idx < 2048) st_llc_b32(flags + idx, 0);
}

// Dual-stream K-split recurrence, 256 WGs x 256 threads (4 waves).
// Pair p = bid&15: stream A rows [32p,+32), stream B rows [512+32p,+32).
// WG j = bid>>4 owns cols [64j,+64) (2 tiles); wave w = K-quarter [256w,+256),
// owns (tile w&1, row-half (w>>1)*16). bw[2][16]=128 regs shared by streams.
// Phase A's {store-drain, flag, poll, load-flight} hide under phase B's
// compute and vice versa. Exact vmcnt ledger via in-order retirement.
__global__ __launch_bounds__(256, 1) void esn_kernel(
    const float* __restrict__ x, const float* __restrict__ Win,
    const unsigned short* __restrict__ wbf,
    unsigned short* __restrict__ h0, unsigned short* __restrict__ h1,
    int* __restrict__ flags) {
  extern __shared__ char smem[];
  char* slA = smem;              // 32 KB: stream A partial slots [tile][prod] 4KB
  char* slB = smem + 32768;      // 32 KB: stream B slots
  char* ctile = smem + 65536;    // 4 KB: per-wave 16x32 bf16 C tiles

  const int bid = blockIdx.x;
  const int p = bid & 15;        // pair (mates share bid%16 -> same XCD heuristic)
  const int j = bid >> 4;        // WG-in-pair 0..15
  const int tid = threadIdx.x;
  const int w = tid >> 6;        // wave 0..3 = K-quarter
  const int lane = tid & 63;
  const int l31 = lane & 31;
  const int hi = lane >> 5;
  const int tw = w & 1;          // own tile
  const int rq = w >> 1;         // own row-half
  const int colbase = j * 64;
  const int n0t = colbase + tw * 32;

  // ---- persistent W fragments: 2 tiles x 16 kk = 128 regs ----
  s8v bw[2][16];
#pragma unroll
  for (int c = 0; c < 2; c++) {
    const unsigned short* wp =
        wbf + (size_t)(colbase + c * 32 + l31) * RS + w * 256 + hi * 8;
#pragma unroll
    for (int kk = 0; kk < 16; kk++) bw[c][kk] = *(const s8v*)(wp + kk * 16);
  }

  // ---- Win hi/lo fragments for OWN tile ----
  union U8 { s8v v; unsigned short u[8]; };
  U8 whi, wlo;
  {
    const float* q = Win + (n0t + l31) * NI + hi * 8;
#pragma unroll
    for (int i = 0; i < 8; i++) {
      float f = q[i];
      unsigned short h16 = f2bf(f);
      whi.u[i] = h16;
      wlo.u[i] = f2bf(f - bf2f(h16));
    }
  }

  int* flA = flags + p * 64;            // stream A: 16 WGs x 4 waves
  int* flB = flags + 1024 + p * 64;
  int* myfA = flA + j * 4 + w;
  int* myfB = flB + j * 4 + w;
  const int* plA = flA + 16 * w;        // producers of wave w's K-quarter
  const int* plB = flB + 16 * w;

  const float* xrA = x + (size_t)(p * 32 + l31) * SL * NI + hi * 8;
  const float* xrB = xrA + (size_t)512 * SL * NI;
  const size_t abA = (((size_t)(32 * w + hi) * NB) + p * 32 + l31) << 4;
  const size_t abB = abA + ((size_t)512 << 4);
  const int c8l = lane >> 4, rloc = lane & 15;
  const size_t stA =
      ((((size_t)(j * 8 + tw * 4 + c8l)) * NB) + p * 32 + rq * 16 + rloc) << 4;
  const size_t stB = stA + ((size_t)512 << 4);
  char* wct = ctile + w * 1024;
  int dead = 0, spins = 0;

#define KBLK4(K0)                                                              \
  _Pragma("unroll") for (int kk = K0; kk < K0 + 4; kk++) {                     \
    union AU { u4v u; s8v s; } au; au.u = al[kk];                              \
    acc0 = __builtin_amdgcn_mfma_f32_32x32x16_bf16(au.s, bw[0][kk], acc0, 0, 0, 0); \
    acc1 = __builtin_amdgcn_mfma_f32_32x32x16_bf16(au.s, bw[1][kk], acc1, 0, 0, 0); \
  }
#define PROJ(X0, X1)                                                           \
  {                                                                            \
    U8 xh, xl;                                                                 \
    float xf[8] = {X0.x, X0.y, X0.z, X0.w, X1.x, X1.y, X1.z, X1.w};            \
    _Pragma("unroll") for (int i = 0; i < 8; i++) {                            \
      unsigned short h16 = f2bf(xf[i]);                                        \
      xh.u[i] = h16; xl.u[i] = f2bf(xf[i] - bf2f(h16));                        \
    }                                                                          \
    f16v z = {};                                                               \
    z = __builtin_amdgcn_mfma_f32_32x32x16_bf16(xh.v, whi.v, z, 0, 0, 0);      \
    z = __builtin_amdgcn_mfma_f32_32x32x16_bf16(xl.v, whi.v, z, 0, 0, 0);      \
    proj = __builtin_amdgcn_mfma_f32_32x32x16_bf16(xh.v, wlo.v, z, 0, 0, 0);   \
  }
#define PARTIALS(SLOT)                                                         \
  _Pragma("unroll") for (int r = 0; r < 16; r++)                               \
    *(float*)((SLOT) + (w << 12) + l31 * 4 + (hi * 16 + r) * 128) = acc0[r];   \
  _Pragma("unroll") for (int r = 0; r < 16; r++)                               \
    *(float*)((SLOT) + ((4 + w) << 12) + l31 * 4 + (hi * 16 + r) * 128) = acc1[r];
#define REDUCE(SLOT)                                                           \
  _Pragma("unroll") for (int rr = 0; rr < 8; rr++) {                           \
    float s = 0.f;                                                             \
    _Pragma("unroll") for (int pr = 0; pr < 4; pr++)                           \
      s += *(const float*)((SLOT) + ((tw * 4 + pr) << 12) + l31 * 4 +          \
                           (hi * 16 + rq * 8 + rr) * 128);                     \
    own[rr] = s;                                                               \
  }
#define EPILOGUE(STOFF, DST)                                                   \
  {                                                                            \
    if (rq == 0) { _Pragma("unroll") for (int rr = 0; rr < 8; rr++) own[rr] += proj[rr]; } \
    else { _Pragma("unroll") for (int rr = 0; rr < 8; rr++) own[rr] += proj[8 + rr]; } \
    _Pragma("unroll") for (int rr = 0; rr < 8; rr++) {                         \
      const int rl = (rr & 3) + 8 * (rr >> 2) + 4 * hi;                        \
      *(unsigned short*)(wct + rl * 64 + l31 * 2) = f2bf(fast_tanh(own[rr]));  \
    }                                                                          \
    asm volatile("s_waitcnt lgkmcnt(0)" ::: "memory");                         \
    __builtin_amdgcn_sched_barrier(0);                                         \
    u4v v = *(const u4v*)(wct + rloc * 64 + c8l * 16);                         \
    st_llc_b128((DST) + (STOFF), v);                                           \
  }
#define POLLCHK(PL, TGT)                                                       \
  if (!dead) {                                                                 \
    int m = min16v(q0, q1, q2, q3);                                            \
    while (m < (TGT)) {                                                        \
      __builtin_amdgcn_s_sleep(2);                                             \
      if (++spins > (1 << 14)) { dead = 1; break; }                            \
      m = min16_block(PL);                                                     \
    }                                                                          \
  }

  // ---- prologue: alA(16) + x(4) + dummy flag(1) = 21 outstanding ----
  u4v al[16];
#pragma unroll
  for (int kk = 0; kk < 16; kk++)
    al[kk] = ld_llc_b128((const char*)h0 + abA + (size_t)kk * (2 * NB * 16));
  float4 xa0 = *(const float4*)xrA, xa1 = *(const float4*)(xrA + 4);
  float4 xb0 = *(const float4*)xrB, xb1 = *(const float4*)(xrB + 4);
  if (lane == 0) st_llc_b32(myfB, 0);   // harmless dummy; fixes vmcnt ledger

  for (int t = 0; t < SL; t++) {
    const char* src = (const char*)((t & 1) ? h1 : h0);
    char* dst = (char*)((t & 1) ? h0 : h1);

    // ===== PHASE A ===== ledger entry: alA16(old), x4, flag1 = 21
    f16v acc0 = {}, acc1 = {};
    WAIT_VM(17); KBLK4(0)
    WAIT_VM(13); KBLK4(4)
    WAIT_VM(9);  KBLK4(8)
    WAIT_VM(5);  KBLK4(12)
    WAIT_VM(1);                          // x drained
    f16v proj;
    PROJ(xa0, xa1)
    PARTIALS(slA)
    __syncthreads();
    u4v q0, q1, q2, q3;
    poll_issue(plB, q0, q1, q2, q3);     // flags fly over the reduce
    float own[8];
    REDUCE(slA)
    WAIT_VM(0);
    POLLCHK(plB, t)
    EPILOGUE(stA, dst)                   // A-store -> 1
#pragma unroll
    for (int kk = 0; kk < 16; kk++)      // alB -> 17 (store oldest)
      al[kk] = ld_llc_b128(src + abB + (size_t)kk * (2 * NB * 16));
    WAIT_VM(16);                         // drains ONLY the A-store
    if (lane == 0) st_llc_b32(myfA, t + 1);   // -> 17

    // ===== PHASE B ===== ledger: alB16(old), flag1
    acc0 = {}; acc1 = {};
    WAIT_VM(13); KBLK4(0)
    WAIT_VM(9);  KBLK4(4)
    WAIT_VM(5);  KBLK4(8)
    WAIT_VM(1);  KBLK4(12)
    PROJ(xb0, xb1)
    PARTIALS(slB)
    __syncthreads();
    poll_issue(plA, q0, q1, q2, q3);
    REDUCE(slB)
    WAIT_VM(0);
    POLLCHK(plA, t + 1)
    EPILOGUE(stB, dst)                   // B-store -> 1
#pragma unroll
    for (int kk = 0; kk < 16; kk++)      // alA(t+1) -> 17
      al[kk] = ld_llc_b128((const char*)dst + abA + (size_t)kk * (2 * NB * 16));
    {
      const size_t xo = (size_t)((t + 1 < SL) ? t + 1 : 0) * NI;   // x -> 21
      xa0 = *(const float4*)(xrA + xo); xa1 = *(const float4*)(xrA + xo + 4);
      xb0 = *(const float4*)(xrB + xo); xb1 = *(const float4*)(xrB + xo + 4);
    }
    WAIT_VM(20);                         // drains ONLY the B-store
    if (lane == 0) st_llc_b32(myfB, t + 1);   // -> 21 = loop invariant
  }
#undef KBLK4
#undef PROJ
#undef PARTIALS
#undef REDUCE
#undef EPILOGUE
#undef POLLCHK
}

// y = h_final @ Wout^T + b ; h in hx layout, read via LLC (bypass stale L1/L2)
__global__ __launch_bounds__(256) void yout_kernel(
    const unsigned short* __restrict__ h, const float* __restrict__ Wout,
    const float* __restrict__ bias, float* __restrict__ y) {
  const int tid = threadIdx.x;
  const int b = (blockIdx.x << 4) + (tid >> 4);
  const int o = tid & 15;
  const float* wr = Wout + (o << 10);
  float s = 0.0f;
  for (int k8 = 0; k8 < RS / 8; k8++) {
    union { u4v u; unsigned short us[8]; } uu;
    uu.u = ld_llc_b128_sync((const char*)h + (((size_t)k8 * NB + b) << 4));
#pragma unroll
    for (int i = 0; i < 8; i++) s += bf2f(uu.us[i]) * wr[k8 * 8 + i];
  }
  y[(b << 4) + o] = s + bias[o];
}

extern "C" void kernel_launch(void* const* d_in, const int* in_sizes, int n_in,
                              void* d_out, int out_size, void* d_ws, size_t ws_size,
                              hipStream_t stream) {
  const float* x = (const float*)d_in[0];
  const float* Win = (const float*)d_in[1];
  const float* W = (const float*)d_in[2];
  const float* Wout = (const float*)d_in[3];
  const float* bias = (const float*)d_in[4];
  float* y = (float*)d_out;

  char* ws = (char*)d_ws;
  unsigned short* h0 = (unsigned short*)ws;                  // 2 MB (final h)
  unsigned short* h1 = (unsigned short*)(ws + (1 << 21));    // 2 MB
  unsigned short* wbf = (unsigned short*)(ws + (2 << 21));   // 2 MB (W bf16)
  int* flags = (int*)(ws + 3 * (size_t)(1 << 21));           // 8 KB (A+B)

  (void)hipFuncSetAttribute((const void*)esn_kernel,
                            hipFuncAttributeMaxDynamicSharedMemorySize, 69632);

  prep_kernel<<<4096, 256, 0, stream>>>(W, wbf, (char*)h0, flags);
  esn_kernel<<<256, 256, 69632, stream>>>(x, Win, wbf, h0, h1, flags);
  yout_kernel<<<64, 256, 0, stream>>>(h0, Wout, bias, y);
}